// Round 1
// baseline (1997.610 us; speedup 1.0000x reference)
//
#include <hip/hip_runtime.h>
#include <math.h>

// ---------------- problem constants ----------------
constexpr int BB   = 32;
constexpr int HH   = 56, WWD = 56, HW = 3136;
constexpr int C0   = 256, C1 = 128, C2 = 64;
constexpr int NA   = 9;
constexpr int NCAND = HW * NA;       // 28224
constexpr int KSEL  = 1024;
constexpr int MAXDET = 100;

// ---------------- weight transpose [oc][k] -> [k][oc] ----------------
__global__ void transpose_w(const float* __restrict__ w, float* __restrict__ wT,
                            int K, int COUT) {
    int i = blockIdx.x * 256 + threadIdx.x;
    if (i >= K * COUT) return;
    int k = i / COUT, oc = i - k * COUT;
    wT[i] = w[oc * K + k];
}

// ---------------- conv3x3 + BN + ReLU (implicit GEMM) ----------------
// tile: 128 pixels x COUT channels, K-chunk = 32, 256 threads
template <int CIN, int COUT>
__global__ __launch_bounds__(256) void conv3x3_bn_relu(
    const float* __restrict__ in,    // [B, CIN, 56, 56]
    const float* __restrict__ wT,    // [CIN*9, COUT]
    const float* __restrict__ cb, const float* __restrict__ gg,
    const float* __restrict__ bb, const float* __restrict__ mm_,
    const float* __restrict__ vv,
    float* __restrict__ out)         // [B, COUT, 56, 56]
{
    constexpr int K    = CIN * 9;
    constexpr int KC   = 32;
    constexpr int MT   = 128;
    constexpr int OCPT = COUT / 16;

    __shared__ float As[KC][MT];
    __shared__ float Bs[KC][COUT];

    const int t = threadIdx.x;
    const int b = blockIdx.y;
    const int pixBase = blockIdx.x * MT;

    const int ocg  = t & 15;     // 0..15
    const int pixg = t >> 4;     // 0..15

    float acc[OCPT][8];
#pragma unroll
    for (int o = 0; o < OCPT; ++o)
#pragma unroll
        for (int j = 0; j < 8; ++j) acc[o][j] = 0.f;

    // A-staging fixed per-thread geometry
    const int mmi = t & 127;
    const int th2 = t >> 7;                 // 0/1
    const int pixA = pixBase + mmi;
    const bool pvalid = pixA < HW;
    const int ya = pixA / 56;
    const int xa = pixA - ya * 56;
    const float* inb = in + (size_t)b * CIN * HW;

    // B-staging geometry
    constexpr int BROWS = 256 / COUT;       // kk rows per pass
    const int ocB = t & (COUT - 1);
    const int thB = t / COUT;

    for (int kc = 0; kc < K; kc += KC) {
        // stage A (gathered im2col), 16 elements per thread
#pragma unroll
        for (int i = 0; i < KC / 2; ++i) {
            int kk  = i * 2 + th2;
            int k   = kc + kk;
            int cin = k / 9;
            int r   = k - cin * 9;
            int ky  = r / 3;
            int kx  = r - ky * 3;
            int iy  = ya + ky - 1;
            int ix  = xa + kx - 1;
            float v = 0.f;
            if (pvalid && (unsigned)iy < 56u && (unsigned)ix < 56u)
                v = inb[cin * HW + iy * 56 + ix];
            As[kk][mmi] = v;
        }
        // stage B (coalesced from transposed weights)
#pragma unroll
        for (int i = 0; i < KC / BROWS; ++i) {
            int kk = i * BROWS + thB;
            Bs[kk][ocB] = wT[(kc + kk) * COUT + ocB];
        }
        __syncthreads();

#pragma unroll 8
        for (int kk = 0; kk < KC; ++kk) {
            float4 a0 = *(const float4*)&As[kk][pixg * 4];
            float4 a1 = *(const float4*)&As[kk][64 + pixg * 4];
            float bf[OCPT];
#pragma unroll
            for (int o4 = 0; o4 < OCPT / 4; ++o4) {
                float4 bv = *(const float4*)&Bs[kk][ocg * OCPT + o4 * 4];
                bf[o4 * 4 + 0] = bv.x; bf[o4 * 4 + 1] = bv.y;
                bf[o4 * 4 + 2] = bv.z; bf[o4 * 4 + 3] = bv.w;
            }
#pragma unroll
            for (int o = 0; o < OCPT; ++o) {
                acc[o][0] += a0.x * bf[o];
                acc[o][1] += a0.y * bf[o];
                acc[o][2] += a0.z * bf[o];
                acc[o][3] += a0.w * bf[o];
                acc[o][4] += a1.x * bf[o];
                acc[o][5] += a1.y * bf[o];
                acc[o][6] += a1.z * bf[o];
                acc[o][7] += a1.w * bf[o];
            }
        }
        __syncthreads();
    }

    // epilogue: fused conv-bias + BN + ReLU
#pragma unroll
    for (int o = 0; o < OCPT; ++o) {
        const int oc = ocg * OCPT + o;
        const float inv = 1.f / sqrtf(vv[oc] + 1e-5f);
        const float scl = gg[oc] * inv;
        const float tb  = bb[oc] + (cb[oc] - mm_[oc]) * scl;
        float* ob = out + ((size_t)b * COUT + oc) * HW;
#pragma unroll
        for (int h = 0; h < 2; ++h) {
            int p0 = pixBase + h * 64 + pixg * 4;
            if (p0 < HW) {
                float4 r;
                r.x = fmaxf(acc[o][h * 4 + 0] * scl + tb, 0.f);
                r.y = fmaxf(acc[o][h * 4 + 1] * scl + tb, 0.f);
                r.z = fmaxf(acc[o][h * 4 + 2] * scl + tb, 0.f);
                r.w = fmaxf(acc[o][h * 4 + 3] * scl + tb, 0.f);
                *(float4*)&ob[p0] = r;
            }
        }
    }
}

// ---------------- conv1x1 (64 -> per-anchor 5) + decode ----------------
// thread = (image, pixel-quad, anchor); computes 5 dots over 64 cin for 4 pixels
__global__ __launch_bounds__(256) void conv1x1_decode(
    const float* __restrict__ x2,    // [B, 64, 56, 56]
    const float* __restrict__ wo,    // [54, 64]
    const float* __restrict__ bo,    // [54]
    float* __restrict__ boxes,       // [B, 28224, 4]
    float* __restrict__ scores)      // [B, 28224]
{
    __shared__ float ws[64 * 56];    // [cin][oc padded to 56]
    for (int i = threadIdx.x; i < 54 * 64; i += 256) {
        int oc = i % 54, c = i / 54;
        ws[c * 56 + oc] = wo[oc * 64 + c];
    }
    __syncthreads();

    int u = blockIdx.x * 256 + threadIdx.x;   // < 32*784*9 = 225792
    int a = u % 9;
    int rest = u / 9;
    int quad = rest % 784;
    int b = rest / 784;
    int pix0 = quad * 4;
    int y = pix0 / 56;
    int x0 = pix0 - y * 56;

    const float* xb = x2 + (size_t)b * 64 * HW + pix0;
    float acc[5][4];
#pragma unroll
    for (int j = 0; j < 5; ++j)
#pragma unroll
        for (int p = 0; p < 4; ++p) acc[j][p] = 0.f;

#pragma unroll 8
    for (int c = 0; c < 64; ++c) {
        float4 xv = *(const float4*)(xb + c * HW);
#pragma unroll
        for (int j = 0; j < 5; ++j) {
            float w = ws[c * 56 + a * 6 + j];
            acc[j][0] += w * xv.x;
            acc[j][1] += w * xv.y;
            acc[j][2] += w * xv.z;
            acc[j][3] += w * xv.w;
        }
    }

    int si = a / 3, ri = a - si * 3;
    float sv = (float)(32 << si);
    float rv = 0.5f * (float)(1 << ri);
    float aw = (sv * rv) / 224.f;
    float ah = (sv / rv) / 224.f;
    float bo0 = bo[a * 6 + 0], bo1 = bo[a * 6 + 1], bo2 = bo[a * 6 + 2];
    float bo3 = bo[a * 6 + 3], bo4 = bo[a * 6 + 4];

#pragma unroll
    for (int p = 0; p < 4; ++p) {
        float p0 = acc[0][p] + bo0;
        float p1 = acc[1][p] + bo1;
        float p2 = acc[2][p] + bo2;
        float p3 = acc[3][p] + bo3;
        float p4 = acc[4][p] + bo4;
        float sx = 1.f / (1.f + expf(-p0));
        float sy = 1.f / (1.f + expf(-p1));
        float pxc = (sx + (float)(x0 + p)) / 56.f;
        float pyc = (sy + (float)y) / 56.f;
        float pw = expf(p2) * aw;
        float ph = expf(p3) * ah;
        float sc = 1.f / (1.f + expf(-p4));
        int n = (y * 56 + x0 + p) * 9 + a;
        float4 bx; bx.x = pxc; bx.y = pyc; bx.z = pw; bx.w = ph;
        *(float4*)&boxes[((size_t)b * NCAND + n) * 4] = bx;
        scores[(size_t)b * NCAND + n] = sc;
    }
}

// ---------------- top-K (exact, stable ties by ascending index) ----------------
__device__ __forceinline__ unsigned fkey(float f) {
    unsigned u = __float_as_uint(f);
    return (u & 0x80000000u) ? ~u : (u | 0x80000000u);
}

__global__ __launch_bounds__(1024) void topk_select(
    const float* __restrict__ scores, const float* __restrict__ boxes,
    float* __restrict__ cbox, float* __restrict__ csc, int* __restrict__ cidx)
{
    const int b = blockIdx.x, t = threadIdx.x;
    const float* sp = scores + (size_t)b * NCAND;
    const int lane = t & 63, w = t >> 6;

    __shared__ unsigned hist[256];
    __shared__ unsigned wsum[16];
    __shared__ unsigned s_sel, s_need, s_tot0, s_tot1;

    unsigned prefix = 0, maskSo = 0;
    int need = KSEL;

    for (int round = 0; round < 4; ++round) {
        int shift = 24 - round * 8;
        if (t < 256) hist[t] = 0;
        __syncthreads();
        for (int i = t; i < NCAND; i += 1024) {
            unsigned u = fkey(sp[i]);
            if ((u & maskSo) == prefix) atomicAdd(&hist[(u >> shift) & 255], 1u);
        }
        __syncthreads();
        if (t == 0) {
            int rem = need;
            unsigned sel = 0;
            for (int v = 255; v >= 0; --v) {
                int c = (int)hist[v];
                if (c >= rem) { sel = (unsigned)v; break; }
                rem -= c;
            }
            s_sel = sel; s_need = (unsigned)rem;
        }
        __syncthreads();
        prefix |= (s_sel << shift);
        maskSo |= (0xFFu << shift);
        need = (int)s_need;
        __syncthreads();
    }

    const unsigned cutoff = prefix;
    const unsigned needT = (unsigned)need;
    unsigned outBase = 0, tieBase = 0;
    const unsigned long long mlt = (1ull << lane) - 1ull;

    for (int c0 = 0; c0 < NCAND; c0 += 1024) {
        int i = c0 + t;
        bool valid = i < NCAND;
        float sc = valid ? sp[i] : 0.f;
        unsigned u = valid ? fkey(sc) : 0u;
        bool gt = valid && (u > cutoff);
        bool eq = valid && (u == cutoff);

        unsigned long long balE = __ballot(eq);
        unsigned lpE = (unsigned)__popcll(balE & mlt);
        if (lane == 0) wsum[w] = (unsigned)__popcll(balE);
        __syncthreads();
        if (t == 0) {
            unsigned run = 0;
            for (int k = 0; k < 16; ++k) { unsigned x = wsum[k]; wsum[k] = run; run += x; }
            s_tot1 = run;
        }
        __syncthreads();
        unsigned tieRank = tieBase + wsum[w] + lpE;
        bool take = gt || (eq && tieRank < needT);
        __syncthreads();

        unsigned long long balT = __ballot(take);
        unsigned lpT = (unsigned)__popcll(balT & mlt);
        if (lane == 0) wsum[w] = (unsigned)__popcll(balT);
        __syncthreads();
        if (t == 0) {
            unsigned run = 0;
            for (int k = 0; k < 16; ++k) { unsigned x = wsum[k]; wsum[k] = run; run += x; }
            s_tot0 = run;
        }
        __syncthreads();
        unsigned pos = outBase + wsum[w] + lpT;
        if (take) {
            float4 bx = *(const float4*)&boxes[((size_t)b * NCAND + i) * 4];
            *(float4*)&cbox[((size_t)b * KSEL + pos) * 4] = bx;
            csc[(size_t)b * KSEL + pos] = sc;
            cidx[(size_t)b * KSEL + pos] = i;
        }
        tieBase += s_tot1;
        outBase += s_tot0;
        __syncthreads();
    }
}

// ---------------- NMS (exact reference semantics) ----------------
__global__ __launch_bounds__(1024) void nms_kernel(
    const float* __restrict__ cbox, const float* __restrict__ csc,
    const int* __restrict__ cidx, float* __restrict__ out)
{
    const int b = blockIdx.x, t = threadIdx.x;
    __shared__ float sx1[KSEL], sy1[KSEL], sx2[KSEL], sy2[KSEL], sar[KSEL];
    __shared__ float rv[16]; __shared__ int ri[16], rs[16];
    __shared__ float chv; __shared__ int chs;

    float4 bx = *(const float4*)&cbox[((size_t)b * KSEL + t) * 4];
    float s = csc[(size_t)b * KSEL + t];
    int oidx = cidx[(size_t)b * KSEL + t];
    s = (s > 0.3f) ? s : -1.f;

    float x1 = bx.x - bx.z / 2.f, y1 = bx.y - bx.w / 2.f;
    float x2_ = bx.x + bx.z / 2.f, y2_ = bx.y + bx.w / 2.f;
    float ar = (x2_ - x1) * (y2_ - y1);
    sx1[t] = x1; sy1[t] = y1; sx2[t] = x2_; sy2[t] = y2_; sar[t] = ar;
    __syncthreads();

    float* ob = out + (size_t)b * MAXDET * 4;
    const int lane = t & 63, w = t >> 6;

    for (int it = 0; it < MAXDET; ++it) {
        float v = s; int id = oidx; int sl = t;
#pragma unroll
        for (int m2 = 1; m2 < 64; m2 <<= 1) {
            float ov = __shfl_xor(v, m2);
            int oi = __shfl_xor(id, m2);
            int os = __shfl_xor(sl, m2);
            if (ov > v || (ov == v && oi < id)) { v = ov; id = oi; sl = os; }
        }
        if (lane == 0) { rv[w] = v; ri[w] = id; rs[w] = sl; }
        __syncthreads();
        if (t == 0) {
            float bv = rv[0]; int bi = ri[0], bsl = rs[0];
            for (int k = 1; k < 16; ++k) {
                if (rv[k] > bv || (rv[k] == bv && ri[k] < bi)) { bv = rv[k]; bi = ri[k]; bsl = rs[k]; }
            }
            chv = bv; chs = bsl;
        }
        __syncthreads();
        float bv = chv; int bsl = chs;
        if (bv <= 0.f) {
            for (int q = it * 4 + t; q < MAXDET * 4; q += 1024) ob[q] = 0.f;
            break;
        }
        if (t == bsl) {
            *(float4*)&ob[it * 4] = bx;
            s = -1.f;
        }
        float cx1 = sx1[bsl], cy1 = sy1[bsl], cx2 = sx2[bsl], cy2 = sy2[bsl], car = sar[bsl];
        float iw = fminf(cx2, x2_) - fmaxf(cx1, x1); iw = fmaxf(iw, 0.f);
        float ih = fminf(cy2, y2_) - fmaxf(cy1, y1); ih = fmaxf(ih, 0.f);
        float inter = iw * ih;
        float uni = (car + ar) - inter;
        float iou = inter / (uni + 1e-16f);
        if (iou > 0.2f) s = -1.f;
        __syncthreads();
    }
}

// ---------------- host launcher ----------------
extern "C" void kernel_launch(void* const* d_in, const int* in_sizes, int n_in,
                              void* d_out, int out_size, void* d_ws, size_t ws_size,
                              hipStream_t stream)
{
    const float* features = (const float*)d_in[0];
    const float* w1 = (const float*)d_in[1];
    const float* b1 = (const float*)d_in[2];
    const float* g1 = (const float*)d_in[3];
    const float* be1 = (const float*)d_in[4];
    const float* m1 = (const float*)d_in[5];
    const float* v1 = (const float*)d_in[6];
    const float* w2 = (const float*)d_in[7];
    const float* b2 = (const float*)d_in[8];
    const float* g2 = (const float*)d_in[9];
    const float* be2 = (const float*)d_in[10];
    const float* m2 = (const float*)d_in[11];
    const float* v2 = (const float*)d_in[12];
    const float* wo = (const float*)d_in[13];
    const float* bo = (const float*)d_in[14];

    char* ws = (char*)d_ws;
    size_t off = 0;
    auto alloc = [&](size_t bytes) {
        char* p = ws + off;
        off += (bytes + 255) / 256 * 256;
        return p;
    };

    float* w1T = (float*)alloc((size_t)2304 * 128 * 4);
    float* w2T = (float*)alloc((size_t)1152 * 64 * 4);
    float* x1  = (float*)alloc((size_t)BB * C1 * HW * 4);   // 51.4 MB
    float* x2  = (float*)alloc((size_t)BB * C2 * HW * 4);   // 25.7 MB
    // boxes/scores alias x1's region (x1 is dead after conv2)
    float* boxes = x1;                                       // 14.5 MB
    float* scores = x1 + (size_t)BB * NCAND * 4;             // 3.6 MB (fits in x1)
    float* cbox = (float*)alloc((size_t)BB * KSEL * 4 * 4);
    float* csc  = (float*)alloc((size_t)BB * KSEL * 4);
    int*   cidx = (int*)alloc((size_t)BB * KSEL * 4);

    transpose_w<<<(2304 * 128 + 255) / 256, 256, 0, stream>>>(w1, w1T, 2304, 128);
    transpose_w<<<(1152 * 64 + 255) / 256, 256, 0, stream>>>(w2, w2T, 1152, 64);

    conv3x3_bn_relu<C0, C1><<<dim3(25, BB), 256, 0, stream>>>(
        features, w1T, b1, g1, be1, m1, v1, x1);
    conv3x3_bn_relu<C1, C2><<<dim3(25, BB), 256, 0, stream>>>(
        x1, w2T, b2, g2, be2, m2, v2, x2);

    conv1x1_decode<<<(BB * 784 * NA) / 256, 256, 0, stream>>>(x2, wo, bo, boxes, scores);

    topk_select<<<BB, 1024, 0, stream>>>(scores, boxes, cbox, csc, cidx);
    nms_kernel<<<BB, 1024, 0, stream>>>(cbox, csc, cidx, (float*)d_out);
}

// Round 2
// 753.048 us; speedup vs baseline: 2.6527x; 2.6527x over previous
//
#include <hip/hip_runtime.h>
#include <math.h>

// ---------------- problem constants ----------------
constexpr int BB   = 32;
constexpr int HW   = 3136;           // 56*56
constexpr int C0   = 256, C1 = 128, C2 = 64;
constexpr int NA   = 9;
constexpr int NCAND = HW * NA;       // 28224
constexpr int KSEL  = 1024;
constexpr int MAXDET = 100;

typedef _Float16 half8 __attribute__((ext_vector_type(8)));
typedef _Float16 half4 __attribute__((ext_vector_type(4)));
typedef float    f32x4 __attribute__((ext_vector_type(4)));

// ---------------- weight reorder [oc][cin*9+r] -> [oc][r*CIN+cin] + fp16 split ----------------
__global__ void split_reorder_w(const float* __restrict__ w,
                                _Float16* __restrict__ whi, _Float16* __restrict__ wlo,
                                int CIN, int COUT) {
    int i = blockIdx.x * 256 + threadIdx.x;
    int K = CIN * 9;
    if (i >= COUT * K) return;
    int oc = i / K, kp = i - oc * K;
    int r = kp / CIN, cin = kp - r * CIN;
    float v = w[oc * K + cin * 9 + r];
    _Float16 h = (_Float16)v;
    whi[i] = h;
    wlo[i] = (_Float16)(v - (float)h);
}

// ---------------- conv3x3 + BN + ReLU via MFMA (fp16x2 emulation) ----------------
// block: 256 threads = 4 waves (2x2). Tile: 128 pixels x COUT.
// K-chunk = 32 (r uniform per chunk thanks to r-major k ordering).
template <int CIN, int COUT>
__global__ __launch_bounds__(256) void conv3x3_mfma(
    const float* __restrict__ in,      // [B, CIN, 3136] fp32
    const _Float16* __restrict__ whi,  // [COUT, 9*CIN]
    const _Float16* __restrict__ wlo,  // [COUT, 9*CIN]
    const float* __restrict__ cb, const float* __restrict__ gg,
    const float* __restrict__ bb, const float* __restrict__ mm_,
    const float* __restrict__ vv,
    float* __restrict__ out)           // [B, COUT, 3136] fp32
{
    constexpr int K    = CIN * 9;
    constexpr int NCH  = K / 32;       // K-chunks
    constexpr int CPR  = CIN / 32;     // chunks per r (8 or 4, pow2)
    constexpr int NF   = COUT / 32;    // N-fragments per wave (4 or 2)
    constexpr int PAD  = 40;           // halves per LDS row (80B, 16B-aligned, conflict-free)

    __shared__ _Float16 lds[(128 + COUT) * PAD * 2];
    _Float16* As_hi = lds;
    _Float16* As_lo = lds + 128 * PAD;
    _Float16* Bs_hi = lds + 128 * PAD * 2;
    _Float16* Bs_lo = lds + 128 * PAD * 2 + COUT * PAD;

    const int t = threadIdx.x;
    const int b = blockIdx.y;
    const int pixBase = blockIdx.x * 128;

    // ---- staging geometry (A) ----
    const int pixA = pixBase + (t & 127);
    const int ya = pixA / 56;
    const int xa = pixA - ya * 56;
    const bool pv = pixA < HW;
    const int kg16 = (t >> 7) * 16;            // 0 or 16
    const float* inb = in + (size_t)b * CIN * HW;
    const int prow = (t & 127) * PAD;

    // ---- staging geometry (B) ----
    const int ocB = t >> 2;                    // 0..63
    const int qB  = (t & 3) * 8;               // 0,8,16,24 halves

    // ---- compute geometry ----
    const int l   = t & 63;
    const int wid = t >> 6;
    const int wm  = wid >> 1, wn = wid & 1;
    const int lr  = l & 15;
    const int k8  = (l >> 4) * 8;

    f32x4 acc[4][NF];
#pragma unroll
    for (int m = 0; m < 4; ++m)
#pragma unroll
        for (int n = 0; n < NF; ++n) acc[m][n] = (f32x4)0.f;

    for (int ch = 0; ch < NCH; ++ch) {
        // ---------- stage A (im2col gather, in-register fp16 split) ----------
        const int r = ch / CPR;                // uniform (CPR is pow2)
        const int cinBase = (ch & (CPR - 1)) * 32;
        const int ky = r / 3, kx = r - (r / 3) * 3;
        const int iy0 = ya + ky - 1, ix0 = xa + kx - 1;
        const bool valid = pv && ((unsigned)iy0 < 56u) && ((unsigned)ix0 < 56u);
        const float* src = inb + (size_t)(cinBase + kg16) * HW + (iy0 * 56 + ix0);

        float v[16];
#pragma unroll
        for (int j = 0; j < 16; ++j) v[j] = 0.f;
        if (valid) {
#pragma unroll
            for (int j = 0; j < 16; ++j) v[j] = src[j * HW];
        }
#pragma unroll
        for (int p8 = 0; p8 < 2; ++p8) {
            half8 h8, l8;
#pragma unroll
            for (int j = 0; j < 8; ++j) {
                float vj = v[p8 * 8 + j];
                _Float16 h = (_Float16)vj;
                h8[j] = h;
                l8[j] = (_Float16)(vj - (float)h);
            }
            *(half8*)&As_hi[prow + kg16 + p8 * 8] = h8;
            *(half8*)&As_lo[prow + kg16 + p8 * 8] = l8;
        }

        // ---------- stage B (pre-split weights, contiguous) ----------
#pragma unroll
        for (int pass = 0; pass < COUT / 64; ++pass) {
            int oc = ocB + pass * 64;
            const size_t gof = (size_t)oc * K + ch * 32 + qB;
            half8 vh = *(const half8*)(whi + gof);
            half8 vl = *(const half8*)(wlo + gof);
            *(half8*)&Bs_hi[oc * PAD + qB] = vh;
            *(half8*)&Bs_lo[oc * PAD + qB] = vl;
        }
        __syncthreads();

        // ---------- MFMA ----------
        half8 bh[NF], bl[NF];
#pragma unroll
        for (int n = 0; n < NF; ++n) {
            int row = wn * (NF * 16) + n * 16 + lr;
            bh[n] = *(const half8*)&Bs_hi[row * PAD + k8];
            bl[n] = *(const half8*)&Bs_lo[row * PAD + k8];
        }
#pragma unroll
        for (int m = 0; m < 4; ++m) {
            int row = wm * 64 + m * 16 + lr;
            half8 ah = *(const half8*)&As_hi[row * PAD + k8];
            half8 al = *(const half8*)&As_lo[row * PAD + k8];
#pragma unroll
            for (int n = 0; n < NF; ++n) {
                acc[m][n] = __builtin_amdgcn_mfma_f32_16x16x32_f16(ah, bh[n], acc[m][n], 0, 0, 0);
                acc[m][n] = __builtin_amdgcn_mfma_f32_16x16x32_f16(ah, bl[n], acc[m][n], 0, 0, 0);
                acc[m][n] = __builtin_amdgcn_mfma_f32_16x16x32_f16(al, bh[n], acc[m][n], 0, 0, 0);
            }
        }
        __syncthreads();
    }

    // ---------- epilogue: bias + BN + ReLU, float4 stores ----------
#pragma unroll
    for (int n = 0; n < NF; ++n) {
        const int oc = wn * (NF * 16) + n * 16 + lr;
        const float inv = 1.f / sqrtf(vv[oc] + 1e-5f);
        const float scl = gg[oc] * inv;
        const float tb  = bb[oc] + (cb[oc] - mm_[oc]) * scl;
        float* ob = out + ((size_t)b * COUT + oc) * HW;
#pragma unroll
        for (int m = 0; m < 4; ++m) {
            int p = pixBase + wm * 64 + m * 16 + (l >> 4) * 4;
            if (p < HW) {
                f32x4 rr;
#pragma unroll
                for (int j = 0; j < 4; ++j)
                    rr[j] = fmaxf(acc[m][n][j] * scl + tb, 0.f);
                *(f32x4*)&ob[p] = rr;
            }
        }
    }
}

// ---------------- conv1x1 (64 -> per-anchor 5) + decode ----------------
__global__ __launch_bounds__(256) void conv1x1_decode(
    const float* __restrict__ x2,    // [B, 64, 56, 56]
    const float* __restrict__ wo,    // [54, 64]
    const float* __restrict__ bo,    // [54]
    float* __restrict__ boxes,       // [B, 28224, 4]
    float* __restrict__ scores)      // [B, 28224]
{
    __shared__ float ws[64 * 56];
    for (int i = threadIdx.x; i < 54 * 64; i += 256) {
        int oc = i % 54, c = i / 54;
        ws[c * 56 + oc] = wo[oc * 64 + c];
    }
    __syncthreads();

    int u = blockIdx.x * 256 + threadIdx.x;
    int a = u % 9;
    int rest = u / 9;
    int quad = rest % 784;
    int b = rest / 784;
    int pix0 = quad * 4;
    int y = pix0 / 56;
    int x0 = pix0 - y * 56;

    const float* xb = x2 + (size_t)b * 64 * HW + pix0;
    float acc[5][4];
#pragma unroll
    for (int j = 0; j < 5; ++j)
#pragma unroll
        for (int p = 0; p < 4; ++p) acc[j][p] = 0.f;

#pragma unroll 8
    for (int c = 0; c < 64; ++c) {
        float4 xv = *(const float4*)(xb + c * HW);
#pragma unroll
        for (int j = 0; j < 5; ++j) {
            float w = ws[c * 56 + a * 6 + j];
            acc[j][0] += w * xv.x;
            acc[j][1] += w * xv.y;
            acc[j][2] += w * xv.z;
            acc[j][3] += w * xv.w;
        }
    }

    int si = a / 3, ri = a - si * 3;
    float sv = (float)(32 << si);
    float rv = 0.5f * (float)(1 << ri);
    float aw = (sv * rv) / 224.f;
    float ah = (sv / rv) / 224.f;
    float bo0 = bo[a * 6 + 0], bo1 = bo[a * 6 + 1], bo2 = bo[a * 6 + 2];
    float bo3 = bo[a * 6 + 3], bo4 = bo[a * 6 + 4];

#pragma unroll
    for (int p = 0; p < 4; ++p) {
        float p0 = acc[0][p] + bo0;
        float p1 = acc[1][p] + bo1;
        float p2 = acc[2][p] + bo2;
        float p3 = acc[3][p] + bo3;
        float p4 = acc[4][p] + bo4;
        float sx = 1.f / (1.f + expf(-p0));
        float sy = 1.f / (1.f + expf(-p1));
        float pxc = (sx + (float)(x0 + p)) / 56.f;
        float pyc = (sy + (float)y) / 56.f;
        float pw = expf(p2) * aw;
        float ph = expf(p3) * ah;
        float sc = 1.f / (1.f + expf(-p4));
        int n = (y * 56 + x0 + p) * 9 + a;
        float4 bx; bx.x = pxc; bx.y = pyc; bx.z = pw; bx.w = ph;
        *(float4*)&boxes[((size_t)b * NCAND + n) * 4] = bx;
        scores[(size_t)b * NCAND + n] = sc;
    }
}

// ---------------- top-K (exact, stable ties by ascending index) ----------------
__device__ __forceinline__ unsigned fkey(float f) {
    unsigned u = __float_as_uint(f);
    return (u & 0x80000000u) ? ~u : (u | 0x80000000u);
}

__global__ __launch_bounds__(1024) void topk_select(
    const float* __restrict__ scores, const float* __restrict__ boxes,
    float* __restrict__ cbox, float* __restrict__ csc, int* __restrict__ cidx)
{
    const int b = blockIdx.x, t = threadIdx.x;
    const float* sp = scores + (size_t)b * NCAND;
    const int lane = t & 63, w = t >> 6;

    __shared__ unsigned hist[256];
    __shared__ unsigned wsum[16];
    __shared__ unsigned s_sel, s_need, s_tot0, s_tot1;

    unsigned prefix = 0, maskSo = 0;
    int need = KSEL;

    for (int round = 0; round < 4; ++round) {
        int shift = 24 - round * 8;
        if (t < 256) hist[t] = 0;
        __syncthreads();
        for (int i = t; i < NCAND; i += 1024) {
            unsigned u = fkey(sp[i]);
            if ((u & maskSo) == prefix) atomicAdd(&hist[(u >> shift) & 255], 1u);
        }
        __syncthreads();
        if (t == 0) {
            int rem = need;
            unsigned sel = 0;
            for (int v = 255; v >= 0; --v) {
                int c = (int)hist[v];
                if (c >= rem) { sel = (unsigned)v; break; }
                rem -= c;
            }
            s_sel = sel; s_need = (unsigned)rem;
        }
        __syncthreads();
        prefix |= (s_sel << shift);
        maskSo |= (0xFFu << shift);
        need = (int)s_need;
        __syncthreads();
    }

    const unsigned cutoff = prefix;
    const unsigned needT = (unsigned)need;
    unsigned outBase = 0, tieBase = 0;
    const unsigned long long mlt = (1ull << lane) - 1ull;

    for (int c0 = 0; c0 < NCAND; c0 += 1024) {
        int i = c0 + t;
        bool valid = i < NCAND;
        float sc = valid ? sp[i] : 0.f;
        unsigned u = valid ? fkey(sc) : 0u;
        bool gt = valid && (u > cutoff);
        bool eq = valid && (u == cutoff);

        unsigned long long balE = __ballot(eq);
        unsigned lpE = (unsigned)__popcll(balE & mlt);
        if (lane == 0) wsum[w] = (unsigned)__popcll(balE);
        __syncthreads();
        if (t == 0) {
            unsigned run = 0;
            for (int k = 0; k < 16; ++k) { unsigned x = wsum[k]; wsum[k] = run; run += x; }
            s_tot1 = run;
        }
        __syncthreads();
        unsigned tieRank = tieBase + wsum[w] + lpE;
        bool take = gt || (eq && tieRank < needT);
        __syncthreads();

        unsigned long long balT = __ballot(take);
        unsigned lpT = (unsigned)__popcll(balT & mlt);
        if (lane == 0) wsum[w] = (unsigned)__popcll(balT);
        __syncthreads();
        if (t == 0) {
            unsigned run = 0;
            for (int k = 0; k < 16; ++k) { unsigned x = wsum[k]; wsum[k] = run; run += x; }
            s_tot0 = run;
        }
        __syncthreads();
        unsigned pos = outBase + wsum[w] + lpT;
        if (take) {
            float4 bx = *(const float4*)&boxes[((size_t)b * NCAND + i) * 4];
            *(float4*)&cbox[((size_t)b * KSEL + pos) * 4] = bx;
            csc[(size_t)b * KSEL + pos] = sc;
            cidx[(size_t)b * KSEL + pos] = i;
        }
        tieBase += s_tot1;
        outBase += s_tot0;
        __syncthreads();
    }
}

// ---------------- NMS (exact reference semantics) ----------------
__global__ __launch_bounds__(1024) void nms_kernel(
    const float* __restrict__ cbox, const float* __restrict__ csc,
    const int* __restrict__ cidx, float* __restrict__ out)
{
    const int b = blockIdx.x, t = threadIdx.x;
    __shared__ float sx1[KSEL], sy1[KSEL], sx2[KSEL], sy2[KSEL], sar[KSEL];
    __shared__ float rv[16]; __shared__ int ri[16], rs[16];
    __shared__ float chv; __shared__ int chs;

    float4 bx = *(const float4*)&cbox[((size_t)b * KSEL + t) * 4];
    float s = csc[(size_t)b * KSEL + t];
    int oidx = cidx[(size_t)b * KSEL + t];
    s = (s > 0.3f) ? s : -1.f;

    float x1 = bx.x - bx.z / 2.f, y1 = bx.y - bx.w / 2.f;
    float x2_ = bx.x + bx.z / 2.f, y2_ = bx.y + bx.w / 2.f;
    float ar = (x2_ - x1) * (y2_ - y1);
    sx1[t] = x1; sy1[t] = y1; sx2[t] = x2_; sy2[t] = y2_; sar[t] = ar;
    __syncthreads();

    float* ob = out + (size_t)b * MAXDET * 4;
    const int lane = t & 63, w = t >> 6;

    for (int it = 0; it < MAXDET; ++it) {
        float v = s; int id = oidx; int sl = t;
#pragma unroll
        for (int m2 = 1; m2 < 64; m2 <<= 1) {
            float ov = __shfl_xor(v, m2);
            int oi = __shfl_xor(id, m2);
            int os = __shfl_xor(sl, m2);
            if (ov > v || (ov == v && oi < id)) { v = ov; id = oi; sl = os; }
        }
        if (lane == 0) { rv[w] = v; ri[w] = id; rs[w] = sl; }
        __syncthreads();
        if (t == 0) {
            float bv = rv[0]; int bi = ri[0], bsl = rs[0];
            for (int k = 1; k < 16; ++k) {
                if (rv[k] > bv || (rv[k] == bv && ri[k] < bi)) { bv = rv[k]; bi = ri[k]; bsl = rs[k]; }
            }
            chv = bv; chs = bsl;
        }
        __syncthreads();
        float bv = chv; int bsl = chs;
        if (bv <= 0.f) {
            for (int q = it * 4 + t; q < MAXDET * 4; q += 1024) ob[q] = 0.f;
            break;
        }
        if (t == bsl) {
            *(float4*)&ob[it * 4] = bx;
            s = -1.f;
        }
        float cx1 = sx1[bsl], cy1 = sy1[bsl], cx2 = sx2[bsl], cy2 = sy2[bsl], car = sar[bsl];
        float iw = fminf(cx2, x2_) - fmaxf(cx1, x1); iw = fmaxf(iw, 0.f);
        float ih = fminf(cy2, y2_) - fmaxf(cy1, y1); ih = fmaxf(ih, 0.f);
        float inter = iw * ih;
        float uni = (car + ar) - inter;
        float iou = inter / (uni + 1e-16f);
        if (iou > 0.2f) s = -1.f;
        __syncthreads();
    }
}

// ---------------- host launcher ----------------
extern "C" void kernel_launch(void* const* d_in, const int* in_sizes, int n_in,
                              void* d_out, int out_size, void* d_ws, size_t ws_size,
                              hipStream_t stream)
{
    const float* features = (const float*)d_in[0];
    const float* w1 = (const float*)d_in[1];
    const float* b1 = (const float*)d_in[2];
    const float* g1 = (const float*)d_in[3];
    const float* be1 = (const float*)d_in[4];
    const float* m1 = (const float*)d_in[5];
    const float* v1 = (const float*)d_in[6];
    const float* w2 = (const float*)d_in[7];
    const float* b2 = (const float*)d_in[8];
    const float* g2 = (const float*)d_in[9];
    const float* be2 = (const float*)d_in[10];
    const float* m2 = (const float*)d_in[11];
    const float* v2 = (const float*)d_in[12];
    const float* wo = (const float*)d_in[13];
    const float* bo = (const float*)d_in[14];

    char* ws = (char*)d_ws;
    size_t off = 0;
    auto alloc = [&](size_t bytes) {
        char* p = ws + off;
        off += (bytes + 255) / 256 * 256;
        return p;
    };

    _Float16* w1hi = (_Float16*)alloc((size_t)C1 * 2304 * 2);
    _Float16* w1lo = (_Float16*)alloc((size_t)C1 * 2304 * 2);
    _Float16* w2hi = (_Float16*)alloc((size_t)C2 * 1152 * 2);
    _Float16* w2lo = (_Float16*)alloc((size_t)C2 * 1152 * 2);
    float* x1  = (float*)alloc((size_t)BB * C1 * HW * 4);   // 51.4 MB
    float* x2  = (float*)alloc((size_t)BB * C2 * HW * 4);   // 25.7 MB
    // boxes/scores alias x1's region (x1 is dead after conv2)
    float* boxes = x1;
    float* scores = x1 + (size_t)BB * NCAND * 4;
    float* cbox = (float*)alloc((size_t)BB * KSEL * 4 * 4);
    float* csc  = (float*)alloc((size_t)BB * KSEL * 4);
    int*   cidx = (int*)alloc((size_t)BB * KSEL * 4);

    split_reorder_w<<<(C1 * 2304 + 255) / 256, 256, 0, stream>>>(w1, w1hi, w1lo, C0, C1);
    split_reorder_w<<<(C2 * 1152 + 255) / 256, 256, 0, stream>>>(w2, w2hi, w2lo, C1, C2);

    conv3x3_mfma<C0, C1><<<dim3(25, BB), 256, 0, stream>>>(
        features, w1hi, w1lo, b1, g1, be1, m1, v1, x1);
    conv3x3_mfma<C1, C2><<<dim3(25, BB), 256, 0, stream>>>(
        x1, w2hi, w2lo, b2, g2, be2, m2, v2, x2);

    conv1x1_decode<<<(BB * 784 * NA) / 256, 256, 0, stream>>>(x2, wo, bo, boxes, scores);

    topk_select<<<BB, 1024, 0, stream>>>(scores, boxes, cbox, csc, cidx);
    nms_kernel<<<BB, 1024, 0, stream>>>(cbox, csc, cidx, (float*)d_out);
}